// Round 10
// baseline (711.712 us; speedup 1.0000x reference)
//
#include <hip/hip_runtime.h>
#include <hip/hip_bf16.h>
#include <stdint.h>

#define D 256

typedef __attribute__((ext_vector_type(8))) short bf16x8;
typedef __attribute__((ext_vector_type(4))) float f32x4;

#define GLOBAL_AS __attribute__((address_space(1)))
#define LDS_AS __attribute__((address_space(3)))

__device__ __forceinline__ unsigned short f2bf(float f) {
  union { float f; unsigned int u; } c; c.f = f;
  unsigned int r = (c.u + 0x7fffu + ((c.u >> 16) & 1u)) >> 16;
  return (unsigned short)r;
}
__device__ __forceinline__ float bf2f(unsigned short h) {
  union { unsigned int u; float f; } c; c.u = ((unsigned int)h) << 16;
  return c.f;
}

// ---------------- prep: x fp32 -> bf16 ----------------
__global__ void convert_x_kernel(const float* __restrict__ x,
                                 unsigned short* __restrict__ xb, int n4) {
  int i = blockIdx.x * blockDim.x + threadIdx.x;
  if (i >= n4) return;
  float4 v = reinterpret_cast<const float4*>(x)[i];
  ushort4 o;
  o.x = f2bf(v.x); o.y = f2bf(v.y); o.z = f2bf(v.z); o.w = f2bf(v.w);
  reinterpret_cast<ushort4*>(xb)[i] = o;
}

// ---- prep: Wt2 big-K layout. Batch b panel: [256 h-rows][KB cols], col r_local*256+d.
// Wt2[(b*256 + h)*KB + rl*256 + d] = bf16(W_r[d][h]); self -> b=0, rl=rbw0.
__global__ void transpose_w2_kernel(const float* __restrict__ Wrel,
                                    const float* __restrict__ Wself,
                                    unsigned short* __restrict__ Wt2,
                                    int R, int RBZ, int KB) {
  __shared__ unsigned short tile[64][65];
  int r = blockIdx.z;
  const float* src = (r == R) ? Wself : (Wrel + (size_t)r * D * D);
  int b, kbase;
  if (r == R) { b = 0; kbase = min(RBZ, R) * 256; }
  else { b = r / RBZ; kbase = (r - b * RBZ) * 256; }
  int d0 = blockIdx.x * 64, h0 = blockIdx.y * 64;
  for (int i = threadIdx.x; i < 64 * 64; i += blockDim.x) {
    int row = i >> 6, col = i & 63;  // row: d, col: h
    tile[row][col] = f2bf(src[(size_t)(d0 + row) * D + h0 + col]);
  }
  __syncthreads();
  for (int i = threadIdx.x; i < 64 * 64; i += blockDim.x) {
    int row = i >> 6, col = i & 63;  // row: h, col: d
    Wt2[((size_t)b * 256 + h0 + row) * KB + kbase + d0 + col] = tile[col][row];
  }
}

// ================= per-(dst,rel) CSR build: bins = dst*R + rel, ev stores src =========
__global__ void hist_kernel(const int* __restrict__ ei, const int* __restrict__ et,
                            int* __restrict__ counts, int E, int M, int R) {
  for (int i = blockIdx.x * blockDim.x + threadIdx.x; i < E;
       i += gridDim.x * blockDim.x) {
    int dst = min(max(ei[E + i], 0), M - 1);
    int rel = min(max(et[i], 0), R - 1);
    atomicAdd(&counts[dst * R + rel], 1);
  }
}

// 1024 bins per block (256 thr x 4 seq)
__global__ void scan1_kernel(const int* __restrict__ counts, int* __restrict__ bsum,
                             int NBINS) {
  __shared__ int red[256];
  int t = threadIdx.x;
  int base = blockIdx.x * 1024 + t * 4;
  int s = 0;
  if (base < NBINS) {
    int4 c = *reinterpret_cast<const int4*>(&counts[base]);
    s = c.x + c.y + c.z + c.w;
  }
  red[t] = s;
  __syncthreads();
  for (int st = 128; st > 0; st >>= 1) {
    if (t < st) red[t] += red[t + st];
    __syncthreads();
  }
  if (t == 0) bsum[blockIdx.x] = red[0];
}

__global__ void scan2_kernel(int* __restrict__ bsum, int NB) {  // exclusive, NB<=1024
  __shared__ int sh[1024];
  int t = threadIdx.x;
  int v = (t < NB) ? bsum[t] : 0;
  sh[t] = v;
  __syncthreads();
  for (int off = 1; off < 1024; off <<= 1) {
    int u = (t >= off) ? sh[t - off] : 0;
    __syncthreads();
    sh[t] += u;
    __syncthreads();
  }
  if (t < NB) bsum[t] = sh[t] - v;
}

__global__ void scan3_kernel(const int* __restrict__ counts, const int* __restrict__ bsum,
                             int* __restrict__ offs, int NBINS) {
  __shared__ int sh[256];
  int t = threadIdx.x;
  int base = blockIdx.x * 1024 + t * 4;
  int c0 = 0, c1 = 0, c2 = 0, c3 = 0;
  if (base < NBINS) {
    int4 c = *reinterpret_cast<const int4*>(&counts[base]);
    c0 = c.x; c1 = c.y; c2 = c.z; c3 = c.w;
  }
  int s = c0 + c1 + c2 + c3;
  sh[t] = s;
  __syncthreads();
  for (int off = 1; off < 256; off <<= 1) {
    int u = (t >= off) ? sh[t - off] : 0;
    __syncthreads();
    sh[t] += u;
    __syncthreads();
  }
  int excl = sh[t] - s + bsum[blockIdx.x];
  if (base < NBINS) {
    offs[base] = excl;
    offs[base + 1] = excl + c0;
    offs[base + 2] = excl + c0 + c1;
    offs[base + 3] = excl + c0 + c1 + c2;
    if (base + 4 == NBINS) offs[NBINS] = excl + s;
  }
}

__global__ void fill_kernel(const int* __restrict__ ei, const int* __restrict__ et,
                            const int* __restrict__ offs, int* __restrict__ cursor,
                            int* __restrict__ ev, int E, int M, int R) {
  for (int i = blockIdx.x * blockDim.x + threadIdx.x; i < E;
       i += gridDim.x * blockDim.x) {
    int dst = min(max(ei[E + i], 0), M - 1);
    int src = min(max(ei[i], 0), M - 1);
    int rel = min(max(et[i], 0), R - 1);
    int bin = dst * R + rel;
    int p = atomicAdd(&cursor[bin], 1);
    ev[offs[bin] + p] = src;
  }
}

// ---- agg: z[dst, rl, :] = sum over edges (dst, rlo+rl) of xb[src]; FIRST adds self slot.
// One wave per dst. xb (25.6MB) is L2/L3-resident -> hot random reads.
template <int FIRST>
__global__ void agg_kernel(const int* __restrict__ offs, const int* __restrict__ ev,
                           const unsigned short* __restrict__ xb,
                           unsigned short* __restrict__ z,
                           int M, int R, int rlo, int rbw, int ZLD) {
  int w = blockIdx.x * (blockDim.x >> 6) + (threadIdx.x >> 6);
  int lane = threadIdx.x & 63;
  if (w >= M) return;
  const int binBase = w * R + rlo;
  unsigned short* zr = z + (size_t)w * ZLD;
  for (int rl = 0; rl < rbw; ++rl) {
    int beg = offs[binBase + rl], end = offs[binBase + rl + 1];
    float a0 = 0, a1 = 0, a2 = 0, a3 = 0;
    int s = beg;
    for (; s + 1 < end; s += 2) {
      int v0 = ev[s], v1 = ev[s + 1];
      ushort4 t0 = *((const ushort4*)(xb + ((size_t)v0 << 8)) + lane);
      ushort4 t1 = *((const ushort4*)(xb + ((size_t)v1 << 8)) + lane);
      a0 += bf2f(t0.x) + bf2f(t1.x);
      a1 += bf2f(t0.y) + bf2f(t1.y);
      a2 += bf2f(t0.z) + bf2f(t1.z);
      a3 += bf2f(t0.w) + bf2f(t1.w);
    }
    if (s < end) {
      ushort4 t = *((const ushort4*)(xb + ((size_t)ev[s] << 8)) + lane);
      a0 += bf2f(t.x); a1 += bf2f(t.y); a2 += bf2f(t.z); a3 += bf2f(t.w);
    }
    ushort4 o;
    o.x = f2bf(a0); o.y = f2bf(a1); o.z = f2bf(a2); o.w = f2bf(a3);
    *((ushort4*)(zr + rl * 256) + lane) = o;
  }
  if (FIRST) {  // self slot at rl = rbw
    ushort4 t = *((const ushort4*)(xb + ((size_t)w << 8)) + lane);
    *((ushort4*)(zr + rbw * 256) + lane) = t;
  }
}

// ---- MFMA GEMM: out(+)= z(M x kTotal) @ Bt(256 x kTotal)^T. 128x128 tile, 4 waves,
// 2-barrier K-loop (proven round-8 structure), panel-swizzled (PANEL=8, ntiles=2).
// FIRST: init with bias; else accumulate out. LAST: fused ReLU.
template <int FIRST, int LAST>
__global__ __launch_bounds__(256) void gemm_z_kernel(
    const unsigned short* __restrict__ A,   // z, ld = ZLD
    const unsigned short* __restrict__ Bt,  // Wt2 panel, ld = KB, 256 rows
    float* __restrict__ out,
    const float* __restrict__ bias,
    int M, int ZLD, int KB, int kTotal) {
  __shared__ unsigned short smem[128 * 64 * 2];  // As 16KB + Bs 16KB
  unsigned short* As = smem;
  unsigned short* Bs = smem + 8192;

  const int tid = threadIdx.x;
  const int lane = tid & 63;
  const int wid = tid >> 6;
  const int wm = wid >> 1, wn = wid & 1;

  const int MBt = (M + 127) >> 7;
  const int per_panel = 16;  // PANEL(8) * ntiles(2)
  const int panel = blockIdx.x / per_panel;
  const int rem = blockIdx.x - panel * per_panel;
  const int pm0 = panel * 8;
  const int ph = min(8, MBt - pm0);
  const int mi = pm0 + rem % ph;
  const int ni = rem / ph;
  const int m0 = mi * 128;
  const int n0 = ni * 128;

  f32x4 acc[4][4] = {};

  for (int k0 = 0; k0 < kTotal; k0 += 64) {
    __syncthreads();  // previous iter's LDS reads done
    for (int i = 0; i < 4; ++i) {
      int chunk = i * 4 + wid;              // 0..15
      int row = chunk * 8 + (lane >> 3);    // 0..127
      int col = (lane & 7) * 8;
      const unsigned short* gb = Bt + (size_t)(n0 + row) * KB + k0 + col;
      __builtin_amdgcn_global_load_lds((GLOBAL_AS void*)(void*)gb,
                                       (LDS_AS void*)(Bs + chunk * 512), 16, 0, 0);
    }
    for (int i = 0; i < 4; ++i) {
      int chunk = i * 4 + wid;
      int row = chunk * 8 + (lane >> 3);
      int col = (lane & 7) * 8;
      int ar = m0 + row; if (ar > M - 1) ar = M - 1;
      const unsigned short* ga = A + (size_t)ar * ZLD + k0 + col;
      __builtin_amdgcn_global_load_lds((GLOBAL_AS void*)(void*)ga,
                                       (LDS_AS void*)(As + chunk * 512), 16, 0, 0);
    }
    __syncthreads();  // staging complete
    for (int kk = 0; kk < 2; ++kk) {
      bf16x8 af[4], bfr[4];
      int kof = kk * 32 + (lane >> 4) * 8;
      for (int mi2 = 0; mi2 < 4; ++mi2)
        af[mi2] = *(const bf16x8*)&As[(wm * 64 + mi2 * 16 + (lane & 15)) * 64 + kof];
      for (int ni2 = 0; ni2 < 4; ++ni2)
        bfr[ni2] = *(const bf16x8*)&Bs[(wn * 64 + ni2 * 16 + (lane & 15)) * 64 + kof];
      for (int mi2 = 0; mi2 < 4; ++mi2)
        for (int ni2 = 0; ni2 < 4; ++ni2)
          acc[mi2][ni2] = __builtin_amdgcn_mfma_f32_16x16x32_bf16(
              af[mi2], bfr[ni2], acc[mi2][ni2], 0, 0, 0);
    }
  }

  for (int mi2 = 0; mi2 < 4; ++mi2)
    for (int ni2 = 0; ni2 < 4; ++ni2) {
      int col = n0 + wn * 64 + ni2 * 16 + (lane & 15);
      int rbase = m0 + wm * 64 + mi2 * 16 + (lane >> 4) * 4;
      float b = FIRST ? bias[col] : 0.f;
      for (int j = 0; j < 4; ++j) {
        int row = rbase + j;
        if (row < M) {
          float v = acc[mi2][ni2][j] + b;
          if (!FIRST) v += out[(size_t)row * 256 + col];
          if (LAST) v = fmaxf(v, 0.f);
          out[(size_t)row * 256 + col] = v;
        }
      }
    }
}

// ---------------- relu in place (fallback path only) ----------------
__global__ void relu_kernel(float* __restrict__ out, int n4) {
  int i = blockIdx.x * blockDim.x + threadIdx.x;
  if (i >= n4) return;
  float4 v = reinterpret_cast<float4*>(out)[i];
  v.x = fmaxf(v.x, 0.f); v.y = fmaxf(v.y, 0.f);
  v.z = fmaxf(v.z, 0.f); v.w = fmaxf(v.w, 0.f);
  reinterpret_cast<float4*>(out)[i] = v;
}

// ======== ws-free fallback tier (correctness only; used only if ws too small) ========
__global__ void fb_self_kernel(const float* __restrict__ x,
                               const float* __restrict__ Wself,
                               const float* __restrict__ bias,
                               float* __restrict__ out, int M) {
  int w = blockIdx.x * (blockDim.x >> 6) + (threadIdx.x >> 6);
  int lane = threadIdx.x & 63;
  int nw = gridDim.x * (blockDim.x >> 6);
  for (int n = w; n < M; n += nw) {
    float a0 = 0, a1 = 0, a2 = 0, a3 = 0;
    const float* xr = x + (size_t)n * 256;
    for (int d = 0; d < 256; ++d) {
      float xv = xr[d];
      float4 wv = *reinterpret_cast<const float4*>(Wself + (size_t)d * 256 + lane * 4);
      a0 = fmaf(xv, wv.x, a0); a1 = fmaf(xv, wv.y, a1);
      a2 = fmaf(xv, wv.z, a2); a3 = fmaf(xv, wv.w, a3);
    }
    float4 b = *reinterpret_cast<const float4*>(bias + lane * 4);
    float4 o = {a0 + b.x, a1 + b.y, a2 + b.z, a3 + b.w};
    *reinterpret_cast<float4*>(out + (size_t)n * 256 + lane * 4) = o;
  }
}

__global__ void fb_edge_kernel(const int* __restrict__ ei, const int* __restrict__ et,
                               const float* __restrict__ x,
                               const float* __restrict__ Wrel,
                               float* __restrict__ out, int E, int M, int R) {
  int w = blockIdx.x * (blockDim.x >> 6) + (threadIdx.x >> 6);
  int lane = threadIdx.x & 63;
  int nw = gridDim.x * (blockDim.x >> 6);
  for (int e = w; e < E; e += nw) {
    int src = min(max(ei[e], 0), M - 1);
    int dst = min(max(ei[E + e], 0), M - 1);
    int rel = min(max(et[e], 0), R - 1);
    const float* xr = x + (size_t)src * 256;
    const float* W = Wrel + (size_t)rel * 256 * 256;
    float a0 = 0, a1 = 0, a2 = 0, a3 = 0;
    for (int d = 0; d < 256; ++d) {
      float xv = xr[d];
      float4 wv = *reinterpret_cast<const float4*>(W + (size_t)d * 256 + lane * 4);
      a0 = fmaf(xv, wv.x, a0); a1 = fmaf(xv, wv.y, a1);
      a2 = fmaf(xv, wv.z, a2); a3 = fmaf(xv, wv.w, a3);
    }
    float* o = out + (size_t)dst * 256 + lane * 4;
    atomicAdd(o + 0, a0);
    atomicAdd(o + 1, a1);
    atomicAdd(o + 2, a2);
    atomicAdd(o + 3, a3);
  }
}

extern "C" void kernel_launch(void* const* d_in, const int* in_sizes, int n_in,
                              void* d_out, int out_size, void* d_ws, size_t ws_size,
                              hipStream_t stream) {
  const float* x = (const float*)d_in[0];
  const int* ei = (const int*)d_in[1];
  const int* et = (const int*)d_in[2];
  const float* Wrel = (const float*)d_in[3];
  const float* Wself = (const float*)d_in[4];
  const float* bias = (const float*)d_in[5];
  float* out = (float*)d_out;

  const int M = in_sizes[0] / D;        // nodes
  const int E = in_sizes[1] / 2;        // edges
  const int R = in_sizes[3] / (D * D);  // relations

  const int n4 = M * D / 4;
  const size_t NBINS = (size_t)M * R;
  const size_t NB2 = (NBINS + 1023) / 1024;
  const size_t intBytes = (4 * NBINS + 1 + NB2 + (size_t)E) * 4;

  // ---- choose relation batch rbz (largest that fits; graph-safe: ws_size only) ----
  int RBZ = 0, nb = 0;
  if (NB2 <= 1024) {
    for (int rbz = R; rbz >= 1; --rbz) {
      int nbc = (R + rbz - 1) / rbz;
      size_t KB = (size_t)(rbz + 1) * 256;
      size_t elems = (size_t)nbc * 256 * KB   // Wt2
                   + (size_t)M * 256          // xb
                   + (size_t)M * KB;          // z
      if (intBytes + 512 + 2 * elems <= ws_size) { RBZ = rbz; nb = nbc; break; }
    }
  }

  if (RBZ == 0) {
    // ---- ws-free fallback: correct for ANY ws_size (never touches d_ws) ----
    fb_self_kernel<<<2048, 256, 0, stream>>>(x, Wself, bias, out, M);
    fb_edge_kernel<<<2048, 256, 0, stream>>>(ei, et, x, Wrel, out, E, M, R);
    relu_kernel<<<(n4 + 255) / 256, 256, 0, stream>>>(out, n4);
    return;
  }

  const int KB = (RBZ + 1) * 256;  // z row stride & Wt2 panel stride

  int* counts = (int*)d_ws;                   // NBINS
  int* cursor = counts + NBINS;               // NBINS
  int* offs = cursor + NBINS;                 // NBINS+1
  int* bsum = offs + NBINS + 1;               // NB2
  int* ev = bsum + NB2;                       // E
  uintptr_t bfp = (uintptr_t)(ev + E);
  bfp = (bfp + 255) & ~(uintptr_t)255;
  unsigned short* Wt2 = (unsigned short*)bfp;
  unsigned short* xb = Wt2 + (size_t)nb * 256 * KB;
  unsigned short* z = xb + (size_t)M * 256;

  // ---- CSR build (per (dst,rel) bins; ev = src) ----
  hipMemsetAsync(counts, 0, 2 * NBINS * 4, stream);  // counts + cursor
  hist_kernel<<<1024, 256, 0, stream>>>(ei, et, counts, E, M, R);
  scan1_kernel<<<(int)NB2, 256, 0, stream>>>(counts, bsum, (int)NBINS);
  scan2_kernel<<<1, 1024, 0, stream>>>(bsum, (int)NB2);
  scan3_kernel<<<(int)NB2, 256, 0, stream>>>(counts, bsum, offs, (int)NBINS);
  fill_kernel<<<1024, 256, 0, stream>>>(ei, et, offs, cursor, ev, E, M, R);

  // ---- prep ----
  transpose_w2_kernel<<<dim3(4, 4, R + 1), 256, 0, stream>>>(Wrel, Wself, Wt2, R, RBZ, KB);
  convert_x_kernel<<<(n4 + 255) / 256, 256, 0, stream>>>(x, xb, n4);

  // ---- batched aggregate-then-transform ----
  const int MBt = (M + 127) / 128;
  const int aggGrid = (M + 3) / 4;
  for (int b = 0; b < nb; ++b) {
    int rlo = b * RBZ;
    int rbw = min(RBZ, R - rlo);
    bool first = (b == 0), last = (b == nb - 1);
    if (first)
      agg_kernel<1><<<aggGrid, 256, 0, stream>>>(offs, ev, xb, z, M, R, rlo, rbw, KB);
    else
      agg_kernel<0><<<aggGrid, 256, 0, stream>>>(offs, ev, xb, z, M, R, rlo, rbw, KB);
    int kTot = rbw * 256 + (first ? 256 : 0);
    const unsigned short* Bt = Wt2 + (size_t)b * 256 * KB;
    if (first && last)
      gemm_z_kernel<1, 1><<<MBt * 2, 256, 0, stream>>>(z, Bt, out, bias, M, KB, KB, kTot);
    else if (first)
      gemm_z_kernel<1, 0><<<MBt * 2, 256, 0, stream>>>(z, Bt, out, bias, M, KB, KB, kTot);
    else if (last)
      gemm_z_kernel<0, 1><<<MBt * 2, 256, 0, stream>>>(z, Bt, out, bias, M, KB, KB, kTot);
    else
      gemm_z_kernel<0, 0><<<MBt * 2, 256, 0, stream>>>(z, Bt, out, bias, M, KB, KB, kTot);
  }
}